// Round 17
// baseline (449.296 us; speedup 1.0000x reference)
//
#include <hip/hip_runtime.h>
#include <hip/hip_bf16.h>
#include <cstddef>

#define BQ 4
#define LQ 2048
#define DQ 512
#define HQ 8
#define HDQ 64
#define KQ 5
#define MAXMQ 10

typedef __attribute__((ext_vector_type(8))) __bf16 bf16x8;
typedef __attribute__((ext_vector_type(4))) __bf16 bf16x4;
typedef __attribute__((ext_vector_type(4))) float f32x4;

__device__ inline void gload_lds16(const void* g, void* l) {
  __builtin_amdgcn_global_load_lds(
      (const __attribute__((address_space(1))) unsigned*)g,
      (__attribute__((address_space(3))) unsigned*)l, 16, 0, 0);
}

__device__ inline unsigned pack_bf16(float a, float b) {
  unsigned short ua = __builtin_bit_cast(unsigned short, (__bf16)a);
  unsigned short ub = __builtin_bit_cast(unsigned short, (__bf16)b);
  return (unsigned)ua | ((unsigned)ub << 16);
}

__device__ inline unsigned pack2(__bf16 a, __bf16 b) {
  return (unsigned)__builtin_bit_cast(unsigned short, a) |
         ((unsigned)__builtin_bit_cast(unsigned short, b) << 16);
}

__device__ inline float bf_lo(unsigned u) {
  return (float)__builtin_bit_cast(__bf16, (unsigned short)(u & 0xffff));
}
__device__ inline float bf_hi(unsigned u) {
  return (float)__builtin_bit_cast(__bf16, (unsigned short)(u >> 16));
}

// ------- merged prep: weight cvt (0..3071) + e_w transpose (3072..3327) -------
// ------- + embedding (3328..11519) -------
__global__ __launch_bounds__(256) void prep_kernel(
    const float* __restrict__ s0, const float* __restrict__ s1,
    const float* __restrict__ s2, const float* __restrict__ s3,
    __bf16* __restrict__ d0, __bf16* __restrict__ d1,
    __bf16* __restrict__ d2, __bf16* __restrict__ d3,
    const float* __restrict__ ew_in, float* __restrict__ ew_out,
    const int* __restrict__ tok, const float* __restrict__ te,
    const float* __restrict__ pe, __bf16* __restrict__ xb) {
  __shared__ float t[32][33];
  const int bid = blockIdx.x;
  if (bid < 3072) {
    size_t g = ((size_t)bid * 256 + threadIdx.x) * 8;
    const float* src; __bf16* dst; size_t e;
    if (g < 1572864)      { src = s0; dst = d0; e = g; }
    else if (g < 2097152) { src = s1; dst = d1; e = g - 1572864; }
    else if (g < 4194304) { src = s2; dst = d2; e = g - 2097152; }
    else                  { src = s3; dst = d3; e = g - 4194304; }
    float4 a = *(const float4*)(src + e);
    float4 b = *(const float4*)(src + e + 4);
    bf16x8 v;
    v[0] = (__bf16)a.x; v[1] = (__bf16)a.y; v[2] = (__bf16)a.z; v[3] = (__bf16)a.w;
    v[4] = (__bf16)b.x; v[5] = (__bf16)b.y; v[6] = (__bf16)b.z; v[7] = (__bf16)b.w;
    *(bf16x8*)(dst + e) = v;
  } else if (bid < 3328) {
    int blk = bid - 3072;
    int bx = blk & 15, by = blk >> 4;
    int cx = threadIdx.x & 31, ry = threadIdx.x >> 5;
    #pragma unroll
    for (int i = 0; i < 4; ++i)
      t[ry + i * 8][cx] = ew_in[(size_t)(by * 32 + ry + i * 8) * 512 + bx * 32 + cx];
    __syncthreads();
    #pragma unroll
    for (int i = 0; i < 4; ++i)
      ew_out[(size_t)(bx * 32 + ry + i * 8) * 512 + by * 32 + cx] = t[cx][ry + i * 8];
  } else {
    int row = bid - 3328;
    int l = row & (LQ - 1);
    int tk = tok[row];
    int d = 2 * threadIdx.x;
    float2 tv = *(const float2*)&te[(size_t)tk * DQ + d];
    float2 pv = *(const float2*)&pe[(size_t)l * DQ + d];
    *(unsigned*)&xb[(size_t)row * DQ + d] = pack_bf16(tv.x + pv.x, tv.y + pv.y);
  }
}

// ------ bf16 MFMA GEMM, 2-phase dbuf, 1D grid + XCD-chunked swizzle (T1) ------
template<bool RELU>
__global__ __launch_bounds__(256) void bgemm_kernel(
    const __bf16* __restrict__ A, const __bf16* __restrict__ W,
    const float* __restrict__ bias, __bf16* __restrict__ Cb,
    int M, int N, int K) {
  __shared__ __bf16 As[2][128][32];
  __shared__ __bf16 Bs[2][128][32];
  const int tid = threadIdx.x;
  const int w = tid >> 6, lane = tid & 63;
  const int lr = lane & 15, lg = lane >> 4;
  const int wr = w >> 1, wc = w & 1;
  const int bid = blockIdx.x;
  const int swz = (bid & 7) * ((int)gridDim.x >> 3) + (bid >> 3);
  const int nbx = N >> 7;
  const int m0 = (swz / nbx) * 128, n0 = (swz % nbx) * 128;

  f32x4 acc[4][4];
  #pragma unroll
  for (int m = 0; m < 4; ++m)
    #pragma unroll
    for (int n = 0; n < 4; ++n) acc[m][n] = f32x4{0.f, 0.f, 0.f, 0.f};

  const int srow = w * 32 + (lane >> 2);
  const int scol = (lane & 3) * 8;
  const __bf16* Ag = A + (size_t)(m0 + srow) * K + scol;
  const __bf16* Bg = W + (size_t)(n0 + srow) * K + scol;

  const int NT = K / 32;

  auto stage = [&](int t, int buf) {
    const int k1 = t * 32;
    gload_lds16(Ag + k1, &As[buf][w * 32][0]);
    gload_lds16(Ag + 16 * K + k1, &As[buf][w * 32 + 16][0]);
    gload_lds16(Bg + k1, &Bs[buf][w * 32][0]);
    gload_lds16(Bg + 16 * K + k1, &Bs[buf][w * 32 + 16][0]);
  };

  auto step = [&](int t, int cur) {
    __syncthreads();
    if (t + 1 < NT) stage(t + 1, cur ^ 1);
    bf16x8 af[4], bfr[4];
    #pragma unroll
    for (int m = 0; m < 4; ++m) af[m] = *(bf16x8*)&As[cur][wr * 64 + m * 16 + lr][lg * 8];
    #pragma unroll
    for (int n = 0; n < 4; ++n) bfr[n] = *(bf16x8*)&Bs[cur][wc * 64 + n * 16 + lr][lg * 8];
    __builtin_amdgcn_s_setprio(1);
    #pragma unroll
    for (int m = 0; m < 4; ++m)
      #pragma unroll
      for (int n = 0; n < 4; ++n)
        acc[m][n] = __builtin_amdgcn_mfma_f32_16x16x32_bf16(af[m], bfr[n], acc[m][n], 0, 0, 0);
    __builtin_amdgcn_s_setprio(0);
  };

  stage(0, 0);
  for (int t = 0; t < NT; t += 2) { step(t, 0); step(t + 1, 1); }

  const int crow = m0 + wr * 64 + lg * 4;
  const int ccol = n0 + wc * 64 + lr;
  #pragma unroll
  for (int n = 0; n < 4; ++n) {
    int gc = ccol + n * 16;
    float bn = bias[gc];
    #pragma unroll
    for (int m = 0; m < 4; ++m) {
      #pragma unroll
      for (int reg = 0; reg < 4; ++reg) {
        int gr = crow + m * 16 + reg;
        float v = acc[m][n][reg] + bn;
        if (RELU) v = fmaxf(v, 0.f);
        Cb[(size_t)gr * N + gc] = (__bf16)v;
      }
    }
  }
}

// ---- split-K x4 bf16 GEMM (1D grid + XCD swizzle): bf16 partials, no bias ----
__global__ __launch_bounds__(256) void bgemm_sk_kernel(
    const __bf16* __restrict__ A, const __bf16* __restrict__ W,
    __bf16* __restrict__ P, int M, int N, int K) {
  __shared__ __bf16 As[2][128][32];
  __shared__ __bf16 Bs[2][128][32];
  const int tid = threadIdx.x;
  const int w = tid >> 6, lane = tid & 63;
  const int lr = lane & 15, lg = lane >> 4;
  const int wr = w >> 1, wc = w & 1;
  const int bid = blockIdx.x;
  const int swz = (bid & 7) * ((int)gridDim.x >> 3) + (bid >> 3);
  const int nbx = N >> 7;                 // 4
  const int nxy = nbx * (M >> 7);         // 256
  const int ks = swz / nxy;               // 0..3
  const int rem = swz % nxy;
  const int m0 = (rem / nbx) * 128, n0 = (rem % nbx) * 128;
  const int kh = K / 4;

  f32x4 acc[4][4];
  #pragma unroll
  for (int m = 0; m < 4; ++m)
    #pragma unroll
    for (int n = 0; n < 4; ++n) acc[m][n] = f32x4{0.f, 0.f, 0.f, 0.f};

  const int srow = w * 32 + (lane >> 2);
  const int scol = (lane & 3) * 8;
  const __bf16* Ag = A + (size_t)(m0 + srow) * K + ks * kh + scol;
  const __bf16* Bg = W + (size_t)(n0 + srow) * K + ks * kh + scol;

  const int NT = kh / 32;

  auto stage = [&](int t, int buf) {
    const int k1 = t * 32;
    gload_lds16(Ag + k1, &As[buf][w * 32][0]);
    gload_lds16(Ag + 16 * K + k1, &As[buf][w * 32 + 16][0]);
    gload_lds16(Bg + k1, &Bs[buf][w * 32][0]);
    gload_lds16(Bg + 16 * K + k1, &Bs[buf][w * 32 + 16][0]);
  };

  auto step = [&](int t, int cur) {
    __syncthreads();
    if (t + 1 < NT) stage(t + 1, cur ^ 1);
    bf16x8 af[4], bfr[4];
    #pragma unroll
    for (int m = 0; m < 4; ++m) af[m] = *(bf16x8*)&As[cur][wr * 64 + m * 16 + lr][lg * 8];
    #pragma unroll
    for (int n = 0; n < 4; ++n) bfr[n] = *(bf16x8*)&Bs[cur][wc * 64 + n * 16 + lr][lg * 8];
    __builtin_amdgcn_s_setprio(1);
    #pragma unroll
    for (int m = 0; m < 4; ++m)
      #pragma unroll
      for (int n = 0; n < 4; ++n)
        acc[m][n] = __builtin_amdgcn_mfma_f32_16x16x32_bf16(af[m], bfr[n], acc[m][n], 0, 0, 0);
    __builtin_amdgcn_s_setprio(0);
  };

  stage(0, 0);
  for (int t = 0; t < NT; t += 2) { step(t, 0); step(t + 1, 1); }

  __bf16* Pk = P + (size_t)ks * M * N;
  const int crow = m0 + wr * 64 + lg * 4;
  const int ccol = n0 + wc * 64 + lr;
  #pragma unroll
  for (int n = 0; n < 4; ++n) {
    int gc = ccol + n * 16;
    #pragma unroll
    for (int m = 0; m < 4; ++m)
      #pragma unroll
      for (int reg = 0; reg < 4; ++reg)
        Pk[(size_t)(crow + m * 16 + reg) * N + gc] = (__bf16)acc[m][n][reg];
  }
}

// -- LN-combine: t = P0+P1+P2+P3+bias+resid(Xb); LN; -> Xb (+hidden +logits) ---
template<bool FIN>
__global__ __launch_bounds__(256) void lnc_kernel(
    const __bf16* __restrict__ P, const float* __restrict__ bias,
    __bf16* __restrict__ Xb, const float* __restrict__ g,
    const float* __restrict__ bb, float* __restrict__ xf,
    const float* __restrict__ sw, const float* __restrict__ sb,
    const float* __restrict__ ew, const float* __restrict__ eb,
    float* __restrict__ osl, float* __restrict__ oel) {
  int row = blockIdx.x;
  int tid = threadIdx.x;
  int d = 2 * tid;
  const size_t SEG = (size_t)(BQ * LQ) * DQ;
  size_t off = (size_t)row * DQ + d;
  unsigned u0 = *(const unsigned*)&P[off];
  unsigned u1 = *(const unsigned*)&P[SEG + off];
  unsigned u2 = *(const unsigned*)&P[2 * SEG + off];
  unsigned u3 = *(const unsigned*)&P[3 * SEG + off];
  float2 bi = *(const float2*)&bias[d];
  unsigned ur = *(const unsigned*)&Xb[off];
  float v0 = bf_lo(u0) + bf_lo(u1) + bf_lo(u2) + bf_lo(u3) + bi.x + bf_lo(ur);
  float v1 = bf_hi(u0) + bf_hi(u1) + bf_hi(u2) + bf_hi(u3) + bi.y + bf_hi(ur);
  float s = v0 + v1, ss = v0 * v0 + v1 * v1;
  #pragma unroll
  for (int off2 = 32; off2; off2 >>= 1) { s += __shfl_xor(s, off2); ss += __shfl_xor(ss, off2); }
  __shared__ float rs[4], rss[4];
  int w = tid >> 6;
  if ((tid & 63) == 0) { rs[w] = s; rss[w] = ss; }
  __syncthreads();
  s = rs[0] + rs[1] + rs[2] + rs[3];
  ss = rss[0] + rss[1] + rss[2] + rss[3];
  float mean = s * (1.f / 512.f);
  float var = ss * (1.f / 512.f) - mean * mean;
  float r = rsqrtf(var + 1e-5f);
  float2 gg = *(const float2*)&g[d];
  float2 bv = *(const float2*)&bb[d];
  float o0 = (v0 - mean) * r * gg.x + bv.x;
  float o1 = (v1 - mean) * r * gg.y + bv.y;
  *(unsigned*)&Xb[off] = pack_bf16(o0, o1);
  if (FIN) {
    float2 of; of.x = o0; of.y = o1;
    *(float2*)&xf[off] = of;
    float2 swv = *(const float2*)&sw[d];
    float2 ewv = *(const float2*)&ew[d];
    float a = o0 * swv.x + o1 * swv.y;
    float b2 = o0 * ewv.x + o1 * ewv.y;
    #pragma unroll
    for (int off2 = 32; off2; off2 >>= 1) { a += __shfl_xor(a, off2); b2 += __shfl_xor(b2, off2); }
    __shared__ float ra[4], rb[4];
    if ((tid & 63) == 0) { ra[w] = a; rb[w] = b2; }
    __syncthreads();
    if (tid == 0) {
      osl[row] = ra[0] + ra[1] + ra[2] + ra[3] + sb[0];
      oel[row] = rb[0] + rb[1] + rb[2] + rb[3] + eb[0];
    }
  }
}

// ---------------- tiny-M GEMM ----------------
template<int MR, bool RELU, bool MASK>
__global__ __launch_bounds__(256) void tinygemm_kernel(
    const float* __restrict__ A, const float* __restrict__ W,
    const float* __restrict__ bias, const int* __restrict__ vs,
    float* __restrict__ C, int N, int K) {
  int n = blockIdx.x * 4 + (threadIdx.x >> 6);
  int lane = threadIdx.x & 63;
  if (n >= N) return;
  const float* wr = W + (size_t)n * K;
  float acc[MR];
  #pragma unroll
  for (int m = 0; m < MR; ++m) acc[m] = 0.f;
  for (int k = lane; k < K; k += 64) {
    float wv = wr[k];
    #pragma unroll
    for (int m = 0; m < MR; ++m)
      acc[m] += A[(size_t)m * K + k] * wv;
  }
  #pragma unroll
  for (int m = 0; m < MR; ++m) {
    #pragma unroll
    for (int off = 32; off; off >>= 1) acc[m] += __shfl_xor(acc[m], off);
  }
  if (lane == 0) {
    float bn = bias ? bias[n] : 0.f;
    #pragma unroll
    for (int m = 0; m < MR; ++m) {
      float v = acc[m] + bn;
      if (RELU) v = fmaxf(v, 0.f);
      if (MASK) v *= (float)vs[m];
      C[(size_t)m * N + n] = v;
    }
  }
}

// ---------------- MFMA flash attention: 8 waves, QBLK=128, fixed-shift softmax -
__global__ __launch_bounds__(512) void attn_mfma_kernel(const __bf16* __restrict__ qkv,
                                                        __bf16* __restrict__ ob) {
  __shared__ __bf16 Ks[2][4096];
  __shared__ __bf16 Vt[2][64][72];
  __shared__ __bf16 Ps[8][1024];

  const int tid = threadIdx.x;
  const int wave = tid >> 6;
  const int lane = tid & 63;
  const int lr = lane & 15;
  const int lg = lane >> 4;

  const int bid = blockIdx.x;
  const int swz = (bid & 7) * 64 + (bid >> 3);
  const int bh = swz >> 4;
  const int qb = swz & 15;
  const int b = bh >> 3, h = bh & 7;
  const int q0 = qb * 128 + wave * 16;

  const __bf16* base = qkv + (size_t)b * LQ * 1536;

  bf16x8 aq[2];
  {
    const __bf16* qp = base + (size_t)(q0 + lr) * 1536 + h * 64 + lg * 8;
    aq[0] = *(const bf16x8*)qp;
    aq[1] = *(const bf16x8*)(qp + 32);
  }

  const int krow = tid >> 3;
  const int kdc = (tid & 7) ^ (krow & 7);
  const __bf16* gK = base + (size_t)krow * 1536 + 512 + h * 64 + kdc * 8;

  const int pr2 = tid >> 4;
  const int dq = tid & 15;
  const int vd0 = dq * 4;
  const __bf16* gV = base + (size_t)(2 * pr2) * 1536 + 1024 + h * 64 + vd0;
  const int pc2 = 2 * (pr2 & 3) + 8 * ((pr2 >> 2) ^ (dq >> 1));

  const int STEP = 64 * 1536;

  float lsum = 0.f;
  f32x4 o_acc[4];
  #pragma unroll
  for (int df = 0; df < 4; ++df) o_acc[df] = f32x4{0.f, 0.f, 0.f, 0.f};

  const float KE = 0.125f * 1.44269504f;

  gload_lds16(gK, &Ks[0][64 * wave * 8]);
  {
    bf16x4 v0 = *(const bf16x4*)gV;
    bf16x4 v1 = *(const bf16x4*)(gV + 1536);
    #pragma unroll
    for (int i = 0; i < 4; ++i)
      *(unsigned*)&Vt[0][vd0 + i][pc2] = pack2(v0[i], v1[i]);
  }
  gK += STEP; gV += STEP;

  auto tile = [&](int cur, bool more) {
    __syncthreads();
    bf16x4 nv0, nv1;
    if (more) {
      gload_lds16(gK, &Ks[cur ^ 1][64 * wave * 8]);
      nv0 = *(const bf16x4*)gV;
      nv1 = *(const bf16x4*)(gV + 1536);
      gK += STEP; gV += STEP;
    }

    f32x4 s[4];
    __builtin_amdgcn_s_setprio(1);
    #pragma unroll
    for (int f = 0; f < 4; ++f) {
      f32x4 acc = f32x4{0.f, 0.f, 0.f, 0.f};
      #pragma unroll
      for (int c = 0; c < 2; ++c) {
        bf16x8 ak = *(bf16x8*)&Ks[cur][(f * 16 + lr) * 64 + (((4 * c + lg) ^ (lr & 7)) << 3)];
        acc = __builtin_amdgcn_mfma_f32_16x16x32_bf16(ak, aq[c], acc, 0, 0, 0);
      }
      s[f] = acc;
    }
    __builtin_amdgcn_s_setprio(0);

    #pragma unroll
    for (int f = 0; f < 4; ++f)
      #pragma unroll
      for (int r = 0; r < 4; ++r) {
        float p = exp2f(s[f][r] * KE);
        s[f][r] = p;
        lsum += p;
      }

    #pragma unroll
    for (int f = 0; f < 4; ++f) {
      uint2 pv;
      pv.x = pack_bf16(s[f][0], s[f][1]);
      pv.y = pack_bf16(s[f][2], s[f][3]);
      int chunk = 2 * f + (lg >> 1);
      int eoff = ((chunk ^ (lr & 7)) << 3) + ((lg & 1) << 2);
      *(uint2*)&Ps[wave][lr * 64 + eoff] = pv;
    }

    #pragma unroll
    for (int kc = 0; kc < 2; ++kc) {
      bf16x8 bp = *(bf16x8*)&Ps[wave][lr * 64 + (((4 * kc + lg) ^ (lr & 7)) << 3)];
      __builtin_amdgcn_s_setprio(1);
      #pragma unroll
      for (int df = 0; df < 4; ++df) {
        int vrow = df * 16 + lr;
        int pb = (((4 * kc + lg) ^ ((vrow >> 3) & 7)) << 3);
        bf16x8 av = *(bf16x8*)&Vt[cur][vrow][pb];
        o_acc[df] = __builtin_amdgcn_mfma_f32_16x16x32_bf16(av, bp, o_acc[df], 0, 0, 0);
      }
      __builtin_amdgcn_s_setprio(0);
    }

    if (more) {
      #pragma unroll
      for (int i = 0; i < 4; ++i)
        *(unsigned*)&Vt[cur ^ 1][vd0 + i][pc2] = pack2(nv0[i], nv1[i]);
    }
  };

  for (int kt = 0; kt < LQ / 64; kt += 2) {
    tile(0, true);
    tile(1, kt + 1 != LQ / 64 - 1);
  }

  lsum += __shfl_xor(lsum, 16);
  lsum += __shfl_xor(lsum, 32);

  float inv = 1.f / lsum;
  __bf16* orow = ob + ((size_t)(b * LQ) + q0 + lr) * DQ + h * 64 + lg * 4;
  #pragma unroll
  for (int df = 0; df < 4; ++df) {
    uint2 ov;
    ov.x = pack_bf16(o_acc[df][0] * inv, o_acc[df][1] * inv);
    ov.y = pack_bf16(o_acc[df][2] * inv, o_acc[df][3] * inv);
    *(uint2*)(orow + df * 16) = ov;
  }
}

// ---------------- top-5 + validity/order (merged) ----------------
__global__ void topkvo_kernel(const float* __restrict__ slog, const float* __restrict__ elog,
                              int* __restrict__ sidx, int* __restrict__ eidx,
                              int* __restrict__ order, int* __restrict__ vs) {
  int b = blockIdx.x;
  int which = threadIdx.x >> 6;
  int lane = threadIdx.x & 63;
  const float* lg = (which ? elog : slog) + (size_t)b * LQ;
  int* outp = (which ? eidx : sidx) + b * KQ;
  __shared__ int sel[2][KQ];
  int ch[KQ];
  for (int k = 0; k < KQ; ++k) {
    float bv = -1e38f; int bi = 1 << 30;
    for (int i = lane; i < LQ; i += 64) {
      bool skip = false;
      for (int t = 0; t < k; ++t) if (ch[t] == i) skip = true;
      float v = lg[i];
      if (!skip && (v > bv || (v == bv && i < bi))) { bv = v; bi = i; }
    }
    #pragma unroll
    for (int off = 32; off; off >>= 1) {
      float ov = __shfl_xor(bv, off); int oi = __shfl_xor(bi, off);
      if (ov > bv || (ov == bv && oi < bi)) { bv = ov; bi = oi; }
    }
    ch[k] = bi;
    if (lane == 0) { outp[k] = bi; sel[which][k] = bi; }
  }
  __syncthreads();
  if (threadIdx.x == 0) {
    int val[KQ];
    for (int k = 0; k < KQ; ++k) {
      int s = sel[0][k], e = sel[1][k];
      val[k] = (e >= s && (e - s) < MAXMQ) ? 1 : 0;
    }
    int j = 0;
    for (int k = 0; k < KQ; ++k) if (val[k])  { order[b * KQ + j] = k; vs[b * KQ + j] = 1; ++j; }
    for (int k = 0; k < KQ; ++k) if (!val[k]) { order[b * KQ + j] = k; vs[b * KQ + j] = 0; ++j; }
  }
}

// ---------------- span features (compacted order) ----------------
__global__ __launch_bounds__(256) void feat_kernel(const float* __restrict__ hidden,
    const int* __restrict__ sidx, const int* __restrict__ eidx,
    const int* __restrict__ order, float* __restrict__ feat) {
  int row = blockIdx.x;
  int b = row / KQ;
  int k = order[row];
  int si = sidx[b * KQ + k], ei = eidx[b * KQ + k];
  const float* hs = hidden + ((size_t)(b * LQ + si)) * DQ;
  const float* he = hidden + ((size_t)(b * LQ + ei)) * DQ;
  float* fr = feat + (size_t)row * (3 * DQ);
  for (int d = threadIdx.x; d < DQ; d += 256) {
    float a = hs[d], c = he[d];
    fr[d] = a; fr[DQ + d] = c; fr[2 * DQ + d] = a * c;
  }
}

// ---------------- scores ----------------
__global__ __launch_bounds__(256) void scores_kernel(const float* __restrict__ cand,
    const float* __restrict__ mp, const float* __restrict__ u, const float* __restrict__ ebias,
    float* __restrict__ oscores) {
  int gw = blockIdx.x * 4 + (threadIdx.x >> 6);
  int lane = threadIdx.x & 63;
  int bj = gw >> 6;
  const float* ce = cand + (size_t)gw * DQ;
  const float* ur = u + (size_t)bj * DQ;
  const float* mr = mp + (size_t)bj * DQ;
  float s = 0.f;
  #pragma unroll
  for (int i = 0; i < 8; ++i) {
    int e = lane + i * 64;
    s += ce[e] * ur[e] + mr[e] * ebias[e];
  }
  #pragma unroll
  for (int off = 32; off; off >>= 1) s += __shfl_xor(s, off);
  if (lane == 0) oscores[gw] = s;
}

extern "C" void kernel_launch(void* const* d_in, const int* in_sizes, int n_in,
                              void* d_out, int out_size, void* d_ws, size_t ws_size,
                              hipStream_t stream) {
  const int*   token_ids = (const int*)d_in[0];
  const float* cand    = (const float*)d_in[1];
  const float* tok_emb = (const float*)d_in[2];
  const float* pos_emb = (const float*)d_in[3];
  const float* ain_w   = (const float*)d_in[4];
  const float* ain_b   = (const float*)d_in[5];
  const float* aout_w  = (const float*)d_in[6];
  const float* aout_b  = (const float*)d_in[7];
  const float* ln1g    = (const float*)d_in[8];
  const float* ln1b    = (const float*)d_in[9];
  const float* fw1     = (const float*)d_in[10];
  const float* fb1     = (const float*)d_in[11];
  const float* fw2     = (const float*)d_in[12];
  const float* fb2     = (const float*)d_in[13];
  const float* ln2g    = (const float*)d_in[14];
  const float* ln2b    = (const float*)d_in[15];
  const float* sw      = (const float*)d_in[16];
  const float* sb      = (const float*)d_in[17];
  const float* ew      = (const float*)d_in[18];
  const float* eb      = (const float*)d_in[19];
  const float* sp_w1   = (const float*)d_in[20];
  const float* sp_b1   = (const float*)d_in[21];
  const float* sp_w2   = (const float*)d_in[22];
  const float* sp_b2   = (const float*)d_in[23];
  const float* m_w     = (const float*)d_in[24];
  const float* m_b     = (const float*)d_in[25];
  const float* e_w     = (const float*)d_in[26];
  const float* e_b     = (const float*)d_in[27];

  const int M = BQ * LQ;           // 8192
  float* out = (float*)d_out;
  float* out_span   = out;                  // [4,5,512]
  float* out_sl     = out + 10240;          // [4,2048]
  float* out_el     = out + 18432;          // [4,2048]
  float* out_hidden = out + 26624;          // [4,2048,512]
  float* out_scores = out + 4220928;        // [4,5,64]

  float* ws  = (float*)d_ws;
  __bf16* BIGb = (__bf16*)ws;                     // [8192,2048] bf16
  __bf16* Xb   = (__bf16*)(ws + 8388608);         // [8192,512] bf16
  __bf16* Ob   = (__bf16*)(ws + 10485760);        // [8192,512] bf16
  __bf16* Pbuf = (__bf16*)(ws + 12582912);        // 4 x [8192,512] bf16 partials
  __bf16* ain_wb  = (__bf16*)(ws + 20971520);
  __bf16* aout_wb = (__bf16*)(ws + 21757952);
  __bf16* fw1b    = (__bf16*)(ws + 22020096);
  __bf16* fw2b    = (__bf16*)(ws + 23068672);
  float* e_wT     = ws + 24117248;
  int*   SIDX  = (int*)(ws + 24379392);
  int*   EIDX  = SIDX + 20;
  int*   ORDER = EIDX + 20;
  int*   VS    = ORDER + 20;
  float* FEAT    = ws + 24379520;
  float* SPANH   = FEAT + 30720;
  float* MP      = SPANH + 10240;
  float* U       = MP + 10240;

  prep_kernel<<<11520, 256, 0, stream>>>(ain_w, aout_w, fw1, fw2,
                                         ain_wb, aout_wb, fw1b, fw2b,
                                         e_w, e_wT, token_ids, tok_emb, pos_emb, Xb);

  for (int l = 0; l < 2; ++l) {
    // qkv (768 blocks, XCD-swizzled)
    bgemm_kernel<false><<<768, 256, 0, stream>>>(
        Xb, ain_wb + (size_t)l * 1536 * 512, ain_b + l * 1536, BIGb, M, 1536, 512);
    attn_mfma_kernel<<<512, 512, 0, stream>>>(BIGb, Ob);
    // out-proj, split-K x4 (1024 blocks)
    bgemm_sk_kernel<<<1024, 256, 0, stream>>>(
        Ob, aout_wb + (size_t)l * 512 * 512, Pbuf, M, 512, 512);
    lnc_kernel<false><<<M, 256, 0, stream>>>(
        Pbuf, aout_b + l * 512, Xb, ln1g + l * 512, ln1b + l * 512,
        nullptr, nullptr, nullptr, nullptr, nullptr, nullptr, nullptr);
    // ffn1 (1024 blocks)
    bgemm_kernel<true><<<1024, 256, 0, stream>>>(
        Xb, fw1b + (size_t)l * 2048 * 512, fb1 + l * 2048, BIGb, M, 2048, 512);
    // ffn2, split-K x4 (1024 blocks)
    bgemm_sk_kernel<<<1024, 256, 0, stream>>>(
        BIGb, fw2b + (size_t)l * 512 * 2048, Pbuf, M, 512, 2048);
    if (l == 0)
      lnc_kernel<false><<<M, 256, 0, stream>>>(
          Pbuf, fb2, Xb, ln2g, ln2b,
          nullptr, nullptr, nullptr, nullptr, nullptr, nullptr, nullptr);
    else
      lnc_kernel<true><<<M, 256, 0, stream>>>(
          Pbuf, fb2 + 512, Xb, ln2g + 512, ln2b + 512,
          out_hidden, sw, sb, ew, eb, out_sl, out_el);
  }

  topkvo_kernel<<<4, 128, 0, stream>>>(out_sl, out_el, SIDX, EIDX, ORDER, VS);
  feat_kernel<<<20, 256, 0, stream>>>(out_hidden, SIDX, EIDX, ORDER, FEAT);
  tinygemm_kernel<20, true, false><<<128, 256, 0, stream>>>(
      FEAT, sp_w1, sp_b1, nullptr, SPANH, 512, 1536);
  tinygemm_kernel<20, false, true><<<128, 256, 0, stream>>>(
      SPANH, sp_w2, sp_b2, VS, out_span, 512, 512);
  tinygemm_kernel<20, false, false><<<128, 256, 0, stream>>>(
      out_span, m_w, m_b, nullptr, MP, 512, 512);
  tinygemm_kernel<20, false, false><<<128, 256, 0, stream>>>(
      MP, e_wT, nullptr, nullptr, U, 512, 512);
  scores_kernel<<<320, 256, 0, stream>>>(cand, MP, U, e_b, out_scores);
}

// Round 18
// 429.076 us; speedup vs baseline: 1.0471x; 1.0471x over previous
//
#include <hip/hip_runtime.h>
#include <hip/hip_bf16.h>
#include <cstddef>

#define BQ 4
#define LQ 2048
#define DQ 512
#define HQ 8
#define HDQ 64
#define KQ 5
#define MAXMQ 10

typedef __attribute__((ext_vector_type(8))) __bf16 bf16x8;
typedef __attribute__((ext_vector_type(4))) __bf16 bf16x4;
typedef __attribute__((ext_vector_type(4))) float f32x4;

__device__ inline void gload_lds16(const void* g, void* l) {
  __builtin_amdgcn_global_load_lds(
      (const __attribute__((address_space(1))) unsigned*)g,
      (__attribute__((address_space(3))) unsigned*)l, 16, 0, 0);
}

__device__ inline unsigned pack_bf16(float a, float b) {
  unsigned short ua = __builtin_bit_cast(unsigned short, (__bf16)a);
  unsigned short ub = __builtin_bit_cast(unsigned short, (__bf16)b);
  return (unsigned)ua | ((unsigned)ub << 16);
}

__device__ inline unsigned pack2(__bf16 a, __bf16 b) {
  return (unsigned)__builtin_bit_cast(unsigned short, a) |
         ((unsigned)__builtin_bit_cast(unsigned short, b) << 16);
}

__device__ inline float bf_lo(unsigned u) {
  return (float)__builtin_bit_cast(__bf16, (unsigned short)(u & 0xffff));
}
__device__ inline float bf_hi(unsigned u) {
  return (float)__builtin_bit_cast(__bf16, (unsigned short)(u >> 16));
}

// ------- merged prep: weight cvt (0..3071) + e_w transpose (3072..3327) -------
// ------- + embedding (3328..11519) -------
__global__ __launch_bounds__(256) void prep_kernel(
    const float* __restrict__ s0, const float* __restrict__ s1,
    const float* __restrict__ s2, const float* __restrict__ s3,
    __bf16* __restrict__ d0, __bf16* __restrict__ d1,
    __bf16* __restrict__ d2, __bf16* __restrict__ d3,
    const float* __restrict__ ew_in, float* __restrict__ ew_out,
    const int* __restrict__ tok, const float* __restrict__ te,
    const float* __restrict__ pe, __bf16* __restrict__ xb) {
  __shared__ float t[32][33];
  const int bid = blockIdx.x;
  if (bid < 3072) {
    size_t g = ((size_t)bid * 256 + threadIdx.x) * 8;
    const float* src; __bf16* dst; size_t e;
    if (g < 1572864)      { src = s0; dst = d0; e = g; }
    else if (g < 2097152) { src = s1; dst = d1; e = g - 1572864; }
    else if (g < 4194304) { src = s2; dst = d2; e = g - 2097152; }
    else                  { src = s3; dst = d3; e = g - 4194304; }
    float4 a = *(const float4*)(src + e);
    float4 b = *(const float4*)(src + e + 4);
    bf16x8 v;
    v[0] = (__bf16)a.x; v[1] = (__bf16)a.y; v[2] = (__bf16)a.z; v[3] = (__bf16)a.w;
    v[4] = (__bf16)b.x; v[5] = (__bf16)b.y; v[6] = (__bf16)b.z; v[7] = (__bf16)b.w;
    *(bf16x8*)(dst + e) = v;
  } else if (bid < 3328) {
    int blk = bid - 3072;
    int bx = blk & 15, by = blk >> 4;
    int cx = threadIdx.x & 31, ry = threadIdx.x >> 5;
    #pragma unroll
    for (int i = 0; i < 4; ++i)
      t[ry + i * 8][cx] = ew_in[(size_t)(by * 32 + ry + i * 8) * 512 + bx * 32 + cx];
    __syncthreads();
    #pragma unroll
    for (int i = 0; i < 4; ++i)
      ew_out[(size_t)(bx * 32 + ry + i * 8) * 512 + by * 32 + cx] = t[cx][ry + i * 8];
  } else {
    int row = bid - 3328;
    int l = row & (LQ - 1);
    int tk = tok[row];
    int d = 2 * threadIdx.x;
    float2 tv = *(const float2*)&te[(size_t)tk * DQ + d];
    float2 pv = *(const float2*)&pe[(size_t)l * DQ + d];
    *(unsigned*)&xb[(size_t)row * DQ + d] = pack_bf16(tv.x + pv.x, tv.y + pv.y);
  }
}

// ------ bf16 MFMA GEMM, 2-phase dbuf, 1D grid + XCD-chunked swizzle (T1) ------
template<bool RELU>
__global__ __launch_bounds__(256) void bgemm_kernel(
    const __bf16* __restrict__ A, const __bf16* __restrict__ W,
    const float* __restrict__ bias, __bf16* __restrict__ Cb,
    int M, int N, int K) {
  __shared__ __bf16 As[2][128][32];
  __shared__ __bf16 Bs[2][128][32];
  const int tid = threadIdx.x;
  const int w = tid >> 6, lane = tid & 63;
  const int lr = lane & 15, lg = lane >> 4;
  const int wr = w >> 1, wc = w & 1;
  const int bid = blockIdx.x;
  const int swz = (bid & 7) * ((int)gridDim.x >> 3) + (bid >> 3);
  const int nbx = N >> 7;
  const int m0 = (swz / nbx) * 128, n0 = (swz % nbx) * 128;

  f32x4 acc[4][4];
  #pragma unroll
  for (int m = 0; m < 4; ++m)
    #pragma unroll
    for (int n = 0; n < 4; ++n) acc[m][n] = f32x4{0.f, 0.f, 0.f, 0.f};

  const int srow = w * 32 + (lane >> 2);
  const int scol = (lane & 3) * 8;
  const __bf16* Ag = A + (size_t)(m0 + srow) * K + scol;
  const __bf16* Bg = W + (size_t)(n0 + srow) * K + scol;

  const int NT = K / 32;

  auto stage = [&](int t, int buf) {
    const int k1 = t * 32;
    gload_lds16(Ag + k1, &As[buf][w * 32][0]);
    gload_lds16(Ag + 16 * K + k1, &As[buf][w * 32 + 16][0]);
    gload_lds16(Bg + k1, &Bs[buf][w * 32][0]);
    gload_lds16(Bg + 16 * K + k1, &Bs[buf][w * 32 + 16][0]);
  };

  auto step = [&](int t, int cur) {
    __syncthreads();
    if (t + 1 < NT) stage(t + 1, cur ^ 1);
    bf16x8 af[4], bfr[4];
    #pragma unroll
    for (int m = 0; m < 4; ++m) af[m] = *(bf16x8*)&As[cur][wr * 64 + m * 16 + lr][lg * 8];
    #pragma unroll
    for (int n = 0; n < 4; ++n) bfr[n] = *(bf16x8*)&Bs[cur][wc * 64 + n * 16 + lr][lg * 8];
    __builtin_amdgcn_s_setprio(1);
    #pragma unroll
    for (int m = 0; m < 4; ++m)
      #pragma unroll
      for (int n = 0; n < 4; ++n)
        acc[m][n] = __builtin_amdgcn_mfma_f32_16x16x32_bf16(af[m], bfr[n], acc[m][n], 0, 0, 0);
    __builtin_amdgcn_s_setprio(0);
  };

  stage(0, 0);
  for (int t = 0; t < NT; t += 2) { step(t, 0); step(t + 1, 1); }

  const int crow = m0 + wr * 64 + lg * 4;
  const int ccol = n0 + wc * 64 + lr;
  #pragma unroll
  for (int n = 0; n < 4; ++n) {
    int gc = ccol + n * 16;
    float bn = bias[gc];
    #pragma unroll
    for (int m = 0; m < 4; ++m) {
      #pragma unroll
      for (int reg = 0; reg < 4; ++reg) {
        int gr = crow + m * 16 + reg;
        float v = acc[m][n][reg] + bn;
        if (RELU) v = fmaxf(v, 0.f);
        Cb[(size_t)gr * N + gc] = (__bf16)v;
      }
    }
  }
}

// ---- split-K x2 bf16 GEMM (1D grid + XCD swizzle): bf16 partials, no bias ----
__global__ __launch_bounds__(256) void bgemm_sk_kernel(
    const __bf16* __restrict__ A, const __bf16* __restrict__ W,
    __bf16* __restrict__ P, int M, int N, int K) {
  __shared__ __bf16 As[2][128][32];
  __shared__ __bf16 Bs[2][128][32];
  const int tid = threadIdx.x;
  const int w = tid >> 6, lane = tid & 63;
  const int lr = lane & 15, lg = lane >> 4;
  const int wr = w >> 1, wc = w & 1;
  const int bid = blockIdx.x;
  const int swz = (bid & 7) * ((int)gridDim.x >> 3) + (bid >> 3);
  const int nbx = N >> 7;                 // 4
  const int nxy = nbx * (M >> 7);         // 256
  const int ks = swz / nxy;               // 0..1
  const int rem = swz % nxy;
  const int m0 = (rem / nbx) * 128, n0 = (rem % nbx) * 128;
  const int kh = K / 2;

  f32x4 acc[4][4];
  #pragma unroll
  for (int m = 0; m < 4; ++m)
    #pragma unroll
    for (int n = 0; n < 4; ++n) acc[m][n] = f32x4{0.f, 0.f, 0.f, 0.f};

  const int srow = w * 32 + (lane >> 2);
  const int scol = (lane & 3) * 8;
  const __bf16* Ag = A + (size_t)(m0 + srow) * K + ks * kh + scol;
  const __bf16* Bg = W + (size_t)(n0 + srow) * K + ks * kh + scol;

  const int NT = kh / 32;

  auto stage = [&](int t, int buf) {
    const int k1 = t * 32;
    gload_lds16(Ag + k1, &As[buf][w * 32][0]);
    gload_lds16(Ag + 16 * K + k1, &As[buf][w * 32 + 16][0]);
    gload_lds16(Bg + k1, &Bs[buf][w * 32][0]);
    gload_lds16(Bg + 16 * K + k1, &Bs[buf][w * 32 + 16][0]);
  };

  auto step = [&](int t, int cur) {
    __syncthreads();
    if (t + 1 < NT) stage(t + 1, cur ^ 1);
    bf16x8 af[4], bfr[4];
    #pragma unroll
    for (int m = 0; m < 4; ++m) af[m] = *(bf16x8*)&As[cur][wr * 64 + m * 16 + lr][lg * 8];
    #pragma unroll
    for (int n = 0; n < 4; ++n) bfr[n] = *(bf16x8*)&Bs[cur][wc * 64 + n * 16 + lr][lg * 8];
    __builtin_amdgcn_s_setprio(1);
    #pragma unroll
    for (int m = 0; m < 4; ++m)
      #pragma unroll
      for (int n = 0; n < 4; ++n)
        acc[m][n] = __builtin_amdgcn_mfma_f32_16x16x32_bf16(af[m], bfr[n], acc[m][n], 0, 0, 0);
    __builtin_amdgcn_s_setprio(0);
  };

  stage(0, 0);
  for (int t = 0; t < NT; t += 2) { step(t, 0); step(t + 1, 1); }

  __bf16* Pk = P + (size_t)ks * M * N;
  const int crow = m0 + wr * 64 + lg * 4;
  const int ccol = n0 + wc * 64 + lr;
  #pragma unroll
  for (int n = 0; n < 4; ++n) {
    int gc = ccol + n * 16;
    #pragma unroll
    for (int m = 0; m < 4; ++m)
      #pragma unroll
      for (int reg = 0; reg < 4; ++reg)
        Pk[(size_t)(crow + m * 16 + reg) * N + gc] = (__bf16)acc[m][n][reg];
  }
}

// ---- LN-combine: t = P0+P1+bias+resid(Xb); LN; -> Xb (+hidden f32 +logits) ----
template<bool FIN>
__global__ __launch_bounds__(256) void lnc_kernel(
    const __bf16* __restrict__ P, const float* __restrict__ bias,
    __bf16* __restrict__ Xb, const float* __restrict__ g,
    const float* __restrict__ bb, float* __restrict__ xf,
    const float* __restrict__ sw, const float* __restrict__ sb,
    const float* __restrict__ ew, const float* __restrict__ eb,
    float* __restrict__ osl, float* __restrict__ oel) {
  int row = blockIdx.x;
  int tid = threadIdx.x;
  int d = 2 * tid;
  unsigned u0 = *(const unsigned*)&P[(size_t)row * DQ + d];
  unsigned u1 = *(const unsigned*)&P[(size_t)(BQ * LQ) * DQ + (size_t)row * DQ + d];
  float2 bi = *(const float2*)&bias[d];
  unsigned ur = *(const unsigned*)&Xb[(size_t)row * DQ + d];
  float v0 = bf_lo(u0) + bf_lo(u1) + bi.x + bf_lo(ur);
  float v1 = bf_hi(u0) + bf_hi(u1) + bi.y + bf_hi(ur);
  float s = v0 + v1, ss = v0 * v0 + v1 * v1;
  #pragma unroll
  for (int off = 32; off; off >>= 1) { s += __shfl_xor(s, off); ss += __shfl_xor(ss, off); }
  __shared__ float rs[4], rss[4];
  int w = tid >> 6;
  if ((tid & 63) == 0) { rs[w] = s; rss[w] = ss; }
  __syncthreads();
  s = rs[0] + rs[1] + rs[2] + rs[3];
  ss = rss[0] + rss[1] + rss[2] + rss[3];
  float mean = s * (1.f / 512.f);
  float var = ss * (1.f / 512.f) - mean * mean;
  float r = rsqrtf(var + 1e-5f);
  float2 gg = *(const float2*)&g[d];
  float2 bv = *(const float2*)&bb[d];
  float o0 = (v0 - mean) * r * gg.x + bv.x;
  float o1 = (v1 - mean) * r * gg.y + bv.y;
  *(unsigned*)&Xb[(size_t)row * DQ + d] = pack_bf16(o0, o1);
  if (FIN) {
    float2 of; of.x = o0; of.y = o1;
    *(float2*)&xf[(size_t)row * DQ + d] = of;
    float2 swv = *(const float2*)&sw[d];
    float2 ewv = *(const float2*)&ew[d];
    float a = o0 * swv.x + o1 * swv.y;
    float b2 = o0 * ewv.x + o1 * ewv.y;
    #pragma unroll
    for (int off = 32; off; off >>= 1) { a += __shfl_xor(a, off); b2 += __shfl_xor(b2, off); }
    __shared__ float ra[4], rb[4];
    if ((tid & 63) == 0) { ra[w] = a; rb[w] = b2; }
    __syncthreads();
    if (tid == 0) {
      osl[row] = ra[0] + ra[1] + ra[2] + ra[3] + sb[0];
      oel[row] = rb[0] + rb[1] + rb[2] + rb[3] + eb[0];
    }
  }
}

// ---------------- tiny-M GEMM ----------------
template<int MR, bool RELU, bool MASK>
__global__ __launch_bounds__(256) void tinygemm_kernel(
    const float* __restrict__ A, const float* __restrict__ W,
    const float* __restrict__ bias, const int* __restrict__ vs,
    float* __restrict__ C, int N, int K) {
  int n = blockIdx.x * 4 + (threadIdx.x >> 6);
  int lane = threadIdx.x & 63;
  if (n >= N) return;
  const float* wr = W + (size_t)n * K;
  float acc[MR];
  #pragma unroll
  for (int m = 0; m < MR; ++m) acc[m] = 0.f;
  for (int k = lane; k < K; k += 64) {
    float wv = wr[k];
    #pragma unroll
    for (int m = 0; m < MR; ++m)
      acc[m] += A[(size_t)m * K + k] * wv;
  }
  #pragma unroll
  for (int m = 0; m < MR; ++m) {
    #pragma unroll
    for (int off = 32; off; off >>= 1) acc[m] += __shfl_xor(acc[m], off);
  }
  if (lane == 0) {
    float bn = bias ? bias[n] : 0.f;
    #pragma unroll
    for (int m = 0; m < MR; ++m) {
      float v = acc[m] + bn;
      if (RELU) v = fmaxf(v, 0.f);
      if (MASK) v *= (float)vs[m];
      C[(size_t)m * N + n] = v;
    }
  }
}

// ---------------- MFMA flash attention: 8 waves, QBLK=128, fixed-shift softmax -
__global__ __launch_bounds__(512) void attn_mfma_kernel(const __bf16* __restrict__ qkv,
                                                        __bf16* __restrict__ ob) {
  __shared__ __bf16 Ks[2][4096];
  __shared__ __bf16 Vt[2][64][72];
  __shared__ __bf16 Ps[8][1024];

  const int tid = threadIdx.x;
  const int wave = tid >> 6;
  const int lane = tid & 63;
  const int lr = lane & 15;
  const int lg = lane >> 4;

  const int bid = blockIdx.x;
  const int swz = (bid & 7) * 64 + (bid >> 3);
  const int bh = swz >> 4;
  const int qb = swz & 15;
  const int b = bh >> 3, h = bh & 7;
  const int q0 = qb * 128 + wave * 16;

  const __bf16* base = qkv + (size_t)b * LQ * 1536;

  bf16x8 aq[2];
  {
    const __bf16* qp = base + (size_t)(q0 + lr) * 1536 + h * 64 + lg * 8;
    aq[0] = *(const bf16x8*)qp;
    aq[1] = *(const bf16x8*)(qp + 32);
  }

  const int krow = tid >> 3;
  const int kdc = (tid & 7) ^ (krow & 7);
  const __bf16* gK = base + (size_t)krow * 1536 + 512 + h * 64 + kdc * 8;

  const int pr2 = tid >> 4;
  const int dq = tid & 15;
  const int vd0 = dq * 4;
  const __bf16* gV = base + (size_t)(2 * pr2) * 1536 + 1024 + h * 64 + vd0;
  const int pc2 = 2 * (pr2 & 3) + 8 * ((pr2 >> 2) ^ (dq >> 1));

  const int STEP = 64 * 1536;

  float lsum = 0.f;
  f32x4 o_acc[4];
  #pragma unroll
  for (int df = 0; df < 4; ++df) o_acc[df] = f32x4{0.f, 0.f, 0.f, 0.f};

  const float KE = 0.125f * 1.44269504f;

  gload_lds16(gK, &Ks[0][64 * wave * 8]);
  {
    bf16x4 v0 = *(const bf16x4*)gV;
    bf16x4 v1 = *(const bf16x4*)(gV + 1536);
    #pragma unroll
    for (int i = 0; i < 4; ++i)
      *(unsigned*)&Vt[0][vd0 + i][pc2] = pack2(v0[i], v1[i]);
  }
  gK += STEP; gV += STEP;

  auto tile = [&](int cur, bool more) {
    __syncthreads();
    bf16x4 nv0, nv1;
    if (more) {
      gload_lds16(gK, &Ks[cur ^ 1][64 * wave * 8]);
      nv0 = *(const bf16x4*)gV;
      nv1 = *(const bf16x4*)(gV + 1536);
      gK += STEP; gV += STEP;
    }

    f32x4 s[4];
    __builtin_amdgcn_s_setprio(1);
    #pragma unroll
    for (int f = 0; f < 4; ++f) {
      f32x4 acc = f32x4{0.f, 0.f, 0.f, 0.f};
      #pragma unroll
      for (int c = 0; c < 2; ++c) {
        bf16x8 ak = *(bf16x8*)&Ks[cur][(f * 16 + lr) * 64 + (((4 * c + lg) ^ (lr & 7)) << 3)];
        acc = __builtin_amdgcn_mfma_f32_16x16x32_bf16(ak, aq[c], acc, 0, 0, 0);
      }
      s[f] = acc;
    }
    __builtin_amdgcn_s_setprio(0);

    #pragma unroll
    for (int f = 0; f < 4; ++f)
      #pragma unroll
      for (int r = 0; r < 4; ++r) {
        float p = exp2f(s[f][r] * KE);
        s[f][r] = p;
        lsum += p;
      }

    #pragma unroll
    for (int f = 0; f < 4; ++f) {
      uint2 pv;
      pv.x = pack_bf16(s[f][0], s[f][1]);
      pv.y = pack_bf16(s[f][2], s[f][3]);
      int chunk = 2 * f + (lg >> 1);
      int eoff = ((chunk ^ (lr & 7)) << 3) + ((lg & 1) << 2);
      *(uint2*)&Ps[wave][lr * 64 + eoff] = pv;
    }

    #pragma unroll
    for (int kc = 0; kc < 2; ++kc) {
      bf16x8 bp = *(bf16x8*)&Ps[wave][lr * 64 + (((4 * kc + lg) ^ (lr & 7)) << 3)];
      __builtin_amdgcn_s_setprio(1);
      #pragma unroll
      for (int df = 0; df < 4; ++df) {
        int vrow = df * 16 + lr;
        int pb = (((4 * kc + lg) ^ ((vrow >> 3) & 7)) << 3);
        bf16x8 av = *(bf16x8*)&Vt[cur][vrow][pb];
        o_acc[df] = __builtin_amdgcn_mfma_f32_16x16x32_bf16(av, bp, o_acc[df], 0, 0, 0);
      }
      __builtin_amdgcn_s_setprio(0);
    }

    if (more) {
      #pragma unroll
      for (int i = 0; i < 4; ++i)
        *(unsigned*)&Vt[cur ^ 1][vd0 + i][pc2] = pack2(nv0[i], nv1[i]);
    }
  };

  for (int kt = 0; kt < LQ / 64; kt += 2) {
    tile(0, true);
    tile(1, kt + 1 != LQ / 64 - 1);
  }

  lsum += __shfl_xor(lsum, 16);
  lsum += __shfl_xor(lsum, 32);

  float inv = 1.f / lsum;
  __bf16* orow = ob + ((size_t)(b * LQ) + q0 + lr) * DQ + h * 64 + lg * 4;
  #pragma unroll
  for (int df = 0; df < 4; ++df) {
    uint2 ov;
    ov.x = pack_bf16(o_acc[df][0] * inv, o_acc[df][1] * inv);
    ov.y = pack_bf16(o_acc[df][2] * inv, o_acc[df][3] * inv);
    *(uint2*)(orow + df * 16) = ov;
  }
}

// ---------------- top-5 + validity/order (merged) ----------------
__global__ void topkvo_kernel(const float* __restrict__ slog, const float* __restrict__ elog,
                              int* __restrict__ sidx, int* __restrict__ eidx,
                              int* __restrict__ order, int* __restrict__ vs) {
  int b = blockIdx.x;
  int which = threadIdx.x >> 6;
  int lane = threadIdx.x & 63;
  const float* lg = (which ? elog : slog) + (size_t)b * LQ;
  int* outp = (which ? eidx : sidx) + b * KQ;
  __shared__ int sel[2][KQ];
  int ch[KQ];
  for (int k = 0; k < KQ; ++k) {
    float bv = -1e38f; int bi = 1 << 30;
    for (int i = lane; i < LQ; i += 64) {
      bool skip = false;
      for (int t = 0; t < k; ++t) if (ch[t] == i) skip = true;
      float v = lg[i];
      if (!skip && (v > bv || (v == bv && i < bi))) { bv = v; bi = i; }
    }
    #pragma unroll
    for (int off = 32; off; off >>= 1) {
      float ov = __shfl_xor(bv, off); int oi = __shfl_xor(bi, off);
      if (ov > bv || (ov == bv && oi < bi)) { bv = ov; bi = oi; }
    }
    ch[k] = bi;
    if (lane == 0) { outp[k] = bi; sel[which][k] = bi; }
  }
  __syncthreads();
  if (threadIdx.x == 0) {
    int val[KQ];
    for (int k = 0; k < KQ; ++k) {
      int s = sel[0][k], e = sel[1][k];
      val[k] = (e >= s && (e - s) < MAXMQ) ? 1 : 0;
    }
    int j = 0;
    for (int k = 0; k < KQ; ++k) if (val[k])  { order[b * KQ + j] = k; vs[b * KQ + j] = 1; ++j; }
    for (int k = 0; k < KQ; ++k) if (!val[k]) { order[b * KQ + j] = k; vs[b * KQ + j] = 0; ++j; }
  }
}

// ---------------- span features (compacted order) ----------------
__global__ __launch_bounds__(256) void feat_kernel(const float* __restrict__ hidden,
    const int* __restrict__ sidx, const int* __restrict__ eidx,
    const int* __restrict__ order, float* __restrict__ feat) {
  int row = blockIdx.x;
  int b = row / KQ;
  int k = order[row];
  int si = sidx[b * KQ + k], ei = eidx[b * KQ + k];
  const float* hs = hidden + ((size_t)(b * LQ + si)) * DQ;
  const float* he = hidden + ((size_t)(b * LQ + ei)) * DQ;
  float* fr = feat + (size_t)row * (3 * DQ);
  for (int d = threadIdx.x; d < DQ; d += 256) {
    float a = hs[d], c = he[d];
    fr[d] = a; fr[DQ + d] = c; fr[2 * DQ + d] = a * c;
  }
}

// ---------------- scores ----------------
__global__ __launch_bounds__(256) void scores_kernel(const float* __restrict__ cand,
    const float* __restrict__ mp, const float* __restrict__ u, const float* __restrict__ ebias,
    float* __restrict__ oscores) {
  int gw = blockIdx.x * 4 + (threadIdx.x >> 6);
  int lane = threadIdx.x & 63;
  int bj = gw >> 6;
  const float* ce = cand + (size_t)gw * DQ;
  const float* ur = u + (size_t)bj * DQ;
  const float* mr = mp + (size_t)bj * DQ;
  float s = 0.f;
  #pragma unroll
  for (int i = 0; i < 8; ++i) {
    int e = lane + i * 64;
    s += ce[e] * ur[e] + mr[e] * ebias[e];
  }
  #pragma unroll
  for (int off = 32; off; off >>= 1) s += __shfl_xor(s, off);
  if (lane == 0) oscores[gw] = s;
}

extern "C" void kernel_launch(void* const* d_in, const int* in_sizes, int n_in,
                              void* d_out, int out_size, void* d_ws, size_t ws_size,
                              hipStream_t stream) {
  const int*   token_ids = (const int*)d_in[0];
  const float* cand    = (const float*)d_in[1];
  const float* tok_emb = (const float*)d_in[2];
  const float* pos_emb = (const float*)d_in[3];
  const float* ain_w   = (const float*)d_in[4];
  const float* ain_b   = (const float*)d_in[5];
  const float* aout_w  = (const float*)d_in[6];
  const float* aout_b  = (const float*)d_in[7];
  const float* ln1g    = (const float*)d_in[8];
  const float* ln1b    = (const float*)d_in[9];
  const float* fw1     = (const float*)d_in[10];
  const float* fb1     = (const float*)d_in[11];
  const float* fw2     = (const float*)d_in[12];
  const float* fb2     = (const float*)d_in[13];
  const float* ln2g    = (const float*)d_in[14];
  const float* ln2b    = (const float*)d_in[15];
  const float* sw      = (const float*)d_in[16];
  const float* sb      = (const float*)d_in[17];
  const float* ew      = (const float*)d_in[18];
  const float* eb      = (const float*)d_in[19];
  const float* sp_w1   = (const float*)d_in[20];
  const float* sp_b1   = (const float*)d_in[21];
  const float* sp_w2   = (const float*)d_in[22];
  const float* sp_b2   = (const float*)d_in[23];
  const float* m_w     = (const float*)d_in[24];
  const float* m_b     = (const float*)d_in[25];
  const float* e_w     = (const float*)d_in[26];
  const float* e_b     = (const float*)d_in[27];

  const int M = BQ * LQ;           // 8192
  float* out = (float*)d_out;
  float* out_span   = out;                  // [4,5,512]
  float* out_sl     = out + 10240;          // [4,2048]
  float* out_el     = out + 18432;          // [4,2048]
  float* out_hidden = out + 26624;          // [4,2048,512]
  float* out_scores = out + 4220928;        // [4,5,64]

  float* ws  = (float*)d_ws;
  __bf16* BIGb = (__bf16*)ws;                     // [8192,2048] bf16
  __bf16* Xb   = (__bf16*)(ws + 8388608);         // [8192,512] bf16
  __bf16* Ob   = (__bf16*)(ws + 10485760);        // [8192,512] bf16
  __bf16* Pbuf = (__bf16*)(ws + 12582912);        // 2 x [8192,512] bf16 partials
  __bf16* ain_wb  = (__bf16*)(ws + 20971520);
  __bf16* aout_wb = (__bf16*)(ws + 21757952);
  __bf16* fw1b    = (__bf16*)(ws + 22020096);
  __bf16* fw2b    = (__bf16*)(ws + 23068672);
  float* e_wT     = ws + 24117248;
  int*   SIDX  = (int*)(ws + 24379392);
  int*   EIDX  = SIDX + 20;
  int*   ORDER = EIDX + 20;
  int*   VS    = ORDER + 20;
  float* FEAT    = ws + 24379520;
  float* SPANH   = FEAT + 30720;
  float* MP      = SPANH + 10240;
  float* U       = MP + 10240;

  prep_kernel<<<11520, 256, 0, stream>>>(ain_w, aout_w, fw1, fw2,
                                         ain_wb, aout_wb, fw1b, fw2b,
                                         e_w, e_wT, token_ids, tok_emb, pos_emb, Xb);

  for (int l = 0; l < 2; ++l) {
    // qkv (768 blocks, XCD-swizzled)
    bgemm_kernel<false><<<768, 256, 0, stream>>>(
        Xb, ain_wb + (size_t)l * 1536 * 512, ain_b + l * 1536, BIGb, M, 1536, 512);
    attn_mfma_kernel<<<512, 512, 0, stream>>>(BIGb, Ob);
    // out-proj, split-K x2 (512 blocks)
    bgemm_sk_kernel<<<512, 256, 0, stream>>>(
        Ob, aout_wb + (size_t)l * 512 * 512, Pbuf, M, 512, 512);
    lnc_kernel<false><<<M, 256, 0, stream>>>(
        Pbuf, aout_b + l * 512, Xb, ln1g + l * 512, ln1b + l * 512,
        nullptr, nullptr, nullptr, nullptr, nullptr, nullptr, nullptr);
    // ffn1 (1024 blocks)
    bgemm_kernel<true><<<1024, 256, 0, stream>>>(
        Xb, fw1b + (size_t)l * 2048 * 512, fb1 + l * 2048, BIGb, M, 2048, 512);
    // ffn2, split-K x2 (512 blocks)
    bgemm_sk_kernel<<<512, 256, 0, stream>>>(
        BIGb, fw2b + (size_t)l * 512 * 2048, Pbuf, M, 512, 2048);
    if (l == 0)
      lnc_kernel<false><<<M, 256, 0, stream>>>(
          Pbuf, fb2, Xb, ln2g, ln2b,
          nullptr, nullptr, nullptr, nullptr, nullptr, nullptr, nullptr);
    else
      lnc_kernel<true><<<M, 256, 0, stream>>>(
          Pbuf, fb2 + 512, Xb, ln2g + 512, ln2b + 512,
          out_hidden, sw, sb, ew, eb, out_sl, out_el);
  }

  topkvo_kernel<<<4, 128, 0, stream>>>(out_sl, out_el, SIDX, EIDX, ORDER, VS);
  feat_kernel<<<20, 256, 0, stream>>>(out_hidden, SIDX, EIDX, ORDER, FEAT);
  tinygemm_kernel<20, true, false><<<128, 256, 0, stream>>>(
      FEAT, sp_w1, sp_b1, nullptr, SPANH, 512, 1536);
  tinygemm_kernel<20, false, true><<<128, 256, 0, stream>>>(
      SPANH, sp_w2, sp_b2, VS, out_span, 512, 512);
  tinygemm_kernel<20, false, false><<<128, 256, 0, stream>>>(
      out_span, m_w, m_b, nullptr, MP, 512, 512);
  tinygemm_kernel<20, false, false><<<128, 256, 0, stream>>>(
      MP, e_wT, nullptr, nullptr, U, 512, 512);
  scores_kernel<<<320, 256, 0, stream>>>(cand, MP, U, e_b, out_scores);
}